// Round 1
// baseline (486.375 us; speedup 1.0000x reference)
//
#include <hip/hip_runtime.h>
#include <hip/hip_bf16.h>

typedef __bf16 bf16x8 __attribute__((ext_vector_type(8)));
typedef __bf16 bf16x4 __attribute__((ext_vector_type(4)));
typedef float  f32x4  __attribute__((ext_vector_type(4)));

// ---------------------------------------------------------------------------
// f32 -> bf16 conversion, 8 elems/thread (n must be a multiple of 8)
// ---------------------------------------------------------------------------
__global__ __launch_bounds__(256) void cvt_kernel(const float* __restrict__ x,
                                                  __bf16* __restrict__ y, long n) {
    long i = ((long)blockIdx.x * 256 + threadIdx.x) * 8;
    if (i >= n) return;
    float4 a = *reinterpret_cast<const float4*>(x + i);
    float4 c = *reinterpret_cast<const float4*>(x + i + 4);
    bf16x8 o;
    o[0] = (__bf16)a.x; o[1] = (__bf16)a.y; o[2] = (__bf16)a.z; o[3] = (__bf16)a.w;
    o[4] = (__bf16)c.x; o[5] = (__bf16)c.y; o[6] = (__bf16)c.z; o[7] = (__bf16)c.w;
    *reinterpret_cast<bf16x8*>(y + i) = o;
}

// ---------------------------------------------------------------------------
// Row softmax of (R[q,:] + mask[b,0,q,:]) -> bf16 probs[b,q,:]
// one block per row, 256 threads, 8 elems/thread (S == 2048)
// ---------------------------------------------------------------------------
__global__ __launch_bounds__(256) void softmax_kernel(const float* __restrict__ R,
                                                      const float* __restrict__ mask,
                                                      __bf16* __restrict__ P, int S) {
    const int q = blockIdx.x, b = blockIdx.y;
    const int t = threadIdx.x;
    const int lane = t & 63, wave = t >> 6;
    const float* rrow = R + (size_t)q * S;
    const float* mrow = mask + ((size_t)b * S + q) * (size_t)S;
    __bf16* prow = P + ((size_t)b * S + q) * (size_t)S;

    float v[8];
#pragma unroll
    for (int i = 0; i < 2; i++) {
        float4 r4 = *reinterpret_cast<const float4*>(rrow + t * 8 + i * 4);
        float4 m4 = *reinterpret_cast<const float4*>(mrow + t * 8 + i * 4);
        v[i * 4 + 0] = r4.x + m4.x;
        v[i * 4 + 1] = r4.y + m4.y;
        v[i * 4 + 2] = r4.z + m4.z;
        v[i * 4 + 3] = r4.w + m4.w;
    }
    float mx = v[0];
#pragma unroll
    for (int i = 1; i < 8; i++) mx = fmaxf(mx, v[i]);
#pragma unroll
    for (int off = 32; off > 0; off >>= 1) mx = fmaxf(mx, __shfl_xor(mx, off));

    __shared__ float smax[4], ssum[4];
    if (lane == 0) smax[wave] = mx;
    __syncthreads();
    mx = fmaxf(fmaxf(smax[0], smax[1]), fmaxf(smax[2], smax[3]));

    float sum = 0.f;
#pragma unroll
    for (int i = 0; i < 8; i++) { v[i] = __expf(v[i] - mx); sum += v[i]; }
#pragma unroll
    for (int off = 32; off > 0; off >>= 1) sum += __shfl_xor(sum, off);
    if (lane == 0) ssum[wave] = sum;
    __syncthreads();
    sum = ssum[0] + ssum[1] + ssum[2] + ssum[3];
    const float inv = 1.0f / sum;

    bf16x8 o;
#pragma unroll
    for (int i = 0; i < 8; i++) o[i] = (__bf16)(v[i] * inv);
    *reinterpret_cast<bf16x8*>(prow + t * 8) = o;
}

// ---------------------------------------------------------------------------
// NT GEMM: C[m,n] = sum_k A[m,k] * B[n,k] (+ bias[n])
// A: M x K row-major (lda), B: N x K row-major (ldb)
// 128x128 tile, BK=64, 256 threads (4 waves, 64x64 each, 4x4 of 16x16x32 MFMA)
// TRANSC: write C^T (C[n,m], ldc = leading dim of C^T) as packed 4x bf16
// CFLOAT: write float C, else bf16
// Requires M%128==0, N%128==0, K%64==0, 16B-aligned pointers, lda/ldb/ldc%8==0
// ---------------------------------------------------------------------------
template <bool TRANSC, bool CFLOAT, bool BIAS>
__global__ __launch_bounds__(256) void gemm_nt_kernel(
    const __bf16* __restrict__ A, const __bf16* __restrict__ B,
    const float* __restrict__ bias, void* __restrict__ Cv,
    int K, int lda, int ldb, int ldc,
    long strideA, long strideB, long strideC) {
    const int t = threadIdx.x;
    const int lane = t & 63;
    const int wave = t >> 6;
    const int lane16 = lane & 15;
    const int quad = lane >> 4;
    const int wm = (wave >> 1) * 64;
    const int wn = (wave & 1) * 64;
    const int bm = blockIdx.y * 128;
    const int bn = blockIdx.x * 128;
    const int bz = blockIdx.z;

    A += (size_t)bz * strideA;
    B += (size_t)bz * strideB;

    __shared__ __bf16 As[128][72];  // +8 pad: 2-way LDS read conflict (free)
    __shared__ __bf16 Bs[128][72];

    const int srow = t >> 3;        // 0..31
    const int scol = (t & 7) * 8;   // 0..56 step 8

    int4 ar[4], br[4];
    auto gload = [&](int kt) {
#pragma unroll
        for (int i = 0; i < 4; i++) {
            ar[i] = *reinterpret_cast<const int4*>(A + (size_t)(bm + srow + i * 32) * lda + kt + scol);
            br[i] = *reinterpret_cast<const int4*>(B + (size_t)(bn + srow + i * 32) * ldb + kt + scol);
        }
    };

    f32x4 acc[4][4];
#pragma unroll
    for (int i = 0; i < 4; i++)
#pragma unroll
        for (int j = 0; j < 4; j++) acc[i][j] = (f32x4){0.f, 0.f, 0.f, 0.f};

    gload(0);
    for (int kt = 0; kt < K; kt += 64) {
        __syncthreads();
#pragma unroll
        for (int i = 0; i < 4; i++) {
            *reinterpret_cast<int4*>(&As[srow + i * 32][scol]) = ar[i];
            *reinterpret_cast<int4*>(&Bs[srow + i * 32][scol]) = br[i];
        }
        __syncthreads();
        if (kt + 64 < K) gload(kt + 64);
#pragma unroll
        for (int s = 0; s < 2; s++) {
            bf16x8 af[4], bfr[4];
#pragma unroll
            for (int mi = 0; mi < 4; mi++)
                af[mi] = *reinterpret_cast<const bf16x8*>(&As[wm + mi * 16 + lane16][s * 32 + quad * 8]);
#pragma unroll
            for (int ni = 0; ni < 4; ni++)
                bfr[ni] = *reinterpret_cast<const bf16x8*>(&Bs[wn + ni * 16 + lane16][s * 32 + quad * 8]);
#pragma unroll
            for (int mi = 0; mi < 4; mi++)
#pragma unroll
                for (int ni = 0; ni < 4; ni++)
                    acc[mi][ni] = __builtin_amdgcn_mfma_f32_16x16x32_bf16(af[mi], bfr[ni], acc[mi][ni], 0, 0, 0);
        }
    }

    // Epilogue. C/D layout: col = lane&15, row = quad*4 + reg  [m89/m91]
    __bf16* Cb = (__bf16*)Cv + (size_t)bz * strideC;
    float* Cf = (float*)Cv + (size_t)bz * strideC;
#pragma unroll
    for (int mi = 0; mi < 4; mi++) {
#pragma unroll
        for (int ni = 0; ni < 4; ni++) {
            const int cm = bm + wm + mi * 16 + quad * 4;
            const int cn = bn + wn + ni * 16 + lane16;
            const float bv = BIAS ? bias[cn] : 0.0f;
            if constexpr (TRANSC) {
                bf16x4 pk;
#pragma unroll
                for (int r = 0; r < 4; r++) pk[r] = (__bf16)(acc[mi][ni][r] + bv);
                *reinterpret_cast<bf16x4*>(Cb + (size_t)cn * ldc + cm) = pk;
            } else if constexpr (CFLOAT) {
#pragma unroll
                for (int r = 0; r < 4; r++)
                    Cf[(size_t)(cm + r) * ldc + cn] = acc[mi][ni][r] + bv;
            } else {
#pragma unroll
                for (int r = 0; r < 4; r++)
                    Cb[(size_t)(cm + r) * ldc + cn] = (__bf16)(acc[mi][ni][r] + bv);
            }
        }
    }
}

// ---------------------------------------------------------------------------
// Launch: cvt x3 -> GEMM1 (values^T) -> softmax -> GEMM2 (P@V) -> GEMM3
// ---------------------------------------------------------------------------
extern "C" void kernel_launch(void* const* d_in, const int* in_sizes, int n_in,
                              void* d_out, int out_size, void* d_ws, size_t ws_size,
                              hipStream_t stream) {
    const float* hidden = (const float*)d_in[0];
    const float* mask   = (const float*)d_in[1];
    const float* R      = (const float*)d_in[2];
    const float* G_w    = (const float*)d_in[3];
    const float* G_b    = (const float*)d_in[4];
    const float* F_w    = (const float*)d_in[5];
    const float* F_b    = (const float*)d_in[6];
    float* out = (float*)d_out;

    constexpr int B = 4, S = 2048, H = 1024;
    char* ws = (char*)d_ws;
    __bf16* h_bf  = (__bf16*)(ws);                   // 16 MB (hidden bf16; later reused as out1)
    __bf16* gw_bf = (__bf16*)(ws + (16ll << 20));    // 2 MB
    __bf16* fw_bf = (__bf16*)(ws + (18ll << 20));    // 2 MB
    __bf16* vt    = (__bf16*)(ws + (20ll << 20));    // 16 MB  values^T [B][H][S]
    __bf16* probs = (__bf16*)(ws + (36ll << 20));    // 32 MB  [B][S][S]
    __bf16* out1  = h_bf;                            // alias (hidden_bf16 dead after GEMM1)

    cvt_kernel<<<(B * S * H) / 8 / 256, 256, 0, stream>>>(hidden, h_bf, (long)B * S * H);
    cvt_kernel<<<(H * H) / 8 / 256, 256, 0, stream>>>(G_w, gw_bf, (long)H * H);
    cvt_kernel<<<(H * H) / 8 / 256, 256, 0, stream>>>(F_w, fw_bf, (long)H * H);

    // GEMM1: Vt[b][h][s] = sum_k hidden[b][s][k] * G_w[h][k] + G_b[h]
    gemm_nt_kernel<true, false, true><<<dim3(H / 128, S / 128, B), 256, 0, stream>>>(
        h_bf, gw_bf, G_b, vt, H, H, H, /*ldc (of C^T)*/ S,
        (long)S * H, 0, (long)H * S);

    // probs[b][q][k] = softmax_k(R[q][k] + mask[b][0][q][k])
    softmax_kernel<<<dim3(S, B), 256, 0, stream>>>(R, mask, probs, S);

    // GEMM2: out1[b][q][h] = sum_s probs[b][q][s] * Vt[b][h][s]
    gemm_nt_kernel<false, false, false><<<dim3(H / 128, S / 128, B), 256, 0, stream>>>(
        probs, vt, nullptr, out1, S, S, S, H,
        (long)S * S, (long)H * S, (long)S * H);

    // GEMM3: out[m][o] = sum_h out1[m][h] * F_w[o][h] + F_b[o]   (m = b*S+s flat)
    gemm_nt_kernel<false, true, true><<<dim3(H / 128, (B * S) / 128, 1), 256, 0, stream>>>(
        out1, fw_bf, F_b, out, H, H, H, H, 0, 0, 0);
}

// Round 2
// 266.524 us; speedup vs baseline: 1.8249x; 1.8249x over previous
//
#include <hip/hip_runtime.h>
#include <hip/hip_bf16.h>

typedef __bf16 bf16x8 __attribute__((ext_vector_type(8)));
typedef __bf16 bf16x4 __attribute__((ext_vector_type(4)));
typedef float  f32x4  __attribute__((ext_vector_type(4)));

#define GPTR(p) ((__attribute__((address_space(1))) void*)(p))
#define LPTR(p) ((__attribute__((address_space(3))) void*)(p))

// ---------------------------------------------------------------------------
// f32 -> bf16 conversion, 8 elems/thread (n must be a multiple of 8)
// ---------------------------------------------------------------------------
__global__ __launch_bounds__(256) void cvt_kernel(const float* __restrict__ x,
                                                  __bf16* __restrict__ y, long n) {
    long i = ((long)blockIdx.x * 256 + threadIdx.x) * 8;
    if (i >= n) return;
    float4 a = *reinterpret_cast<const float4*>(x + i);
    float4 c = *reinterpret_cast<const float4*>(x + i + 4);
    bf16x8 o;
    o[0] = (__bf16)a.x; o[1] = (__bf16)a.y; o[2] = (__bf16)a.z; o[3] = (__bf16)a.w;
    o[4] = (__bf16)c.x; o[5] = (__bf16)c.y; o[6] = (__bf16)c.z; o[7] = (__bf16)c.w;
    *reinterpret_cast<bf16x8*>(y + i) = o;
}

// ---------------------------------------------------------------------------
// Transpose + cvt: y[c][r] = (bf16)x[r][c], x is n x n fp32. 64x64 LDS tiles.
// ---------------------------------------------------------------------------
__global__ __launch_bounds__(256) void transpose_cvt_kernel(const float* __restrict__ x,
                                                            __bf16* __restrict__ y, int n) {
    __shared__ float tile[64][65];
    const int bx = blockIdx.x * 64;  // col base in x
    const int by = blockIdx.y * 64;  // row base in x
    const int t = threadIdx.x;
    const int tr = t >> 4;
    const int tc = (t & 15) * 4;
#pragma unroll
    for (int i = 0; i < 4; i++) {
        float4 v = *reinterpret_cast<const float4*>(&x[(size_t)(by + tr + i * 16) * n + bx + tc]);
        tile[tr + i * 16][tc + 0] = v.x;
        tile[tr + i * 16][tc + 1] = v.y;
        tile[tr + i * 16][tc + 2] = v.z;
        tile[tr + i * 16][tc + 3] = v.w;
    }
    __syncthreads();
    const int wr = t >> 2;           // row in y-tile (= col in x)
    const int wc = (t & 3) * 16;     // col in y-tile (= row in x)
    bf16x8 o0, o1;
#pragma unroll
    for (int j = 0; j < 8; j++) o0[j] = (__bf16)tile[wc + j][wr];
#pragma unroll
    for (int j = 0; j < 8; j++) o1[j] = (__bf16)tile[wc + 8 + j][wr];
    *reinterpret_cast<bf16x8*>(&y[(size_t)(bx + wr) * n + by + wc]) = o0;
    *reinterpret_cast<bf16x8*>(&y[(size_t)(bx + wr) * n + by + wc + 8]) = o1;
}

// ---------------------------------------------------------------------------
// b2[o] = sum_h Fw[o][h] * Gb[h] + Fb[o]    (fp32, exact-ish; tiny)
// ---------------------------------------------------------------------------
__global__ __launch_bounds__(256) void gemv_bias_kernel(const float* __restrict__ Fw,
                                                        const float* __restrict__ Gb,
                                                        const float* __restrict__ Fb,
                                                        float* __restrict__ b2, int H) {
    const int o = blockIdx.x;
    float s = 0.f;
    for (int h = threadIdx.x; h < H; h += 256) s += Fw[(size_t)o * H + h] * Gb[h];
#pragma unroll
    for (int off = 32; off > 0; off >>= 1) s += __shfl_xor(s, off);
    __shared__ float ss[4];
    if ((threadIdx.x & 63) == 0) ss[threadIdx.x >> 6] = s;
    __syncthreads();
    if (threadIdx.x == 0) b2[o] = ss[0] + ss[1] + ss[2] + ss[3] + Fb[o];
}

// ---------------------------------------------------------------------------
// Row softmax of (R[q,:] + mask[b,0,q,:]) -> bf16 probs[b,q,:]
// ---------------------------------------------------------------------------
__global__ __launch_bounds__(256) void softmax_kernel(const float* __restrict__ R,
                                                      const float* __restrict__ mask,
                                                      __bf16* __restrict__ P, int S) {
    const int q = blockIdx.x, b = blockIdx.y;
    const int t = threadIdx.x;
    const int lane = t & 63, wave = t >> 6;
    const float* rrow = R + (size_t)q * S;
    const float* mrow = mask + ((size_t)b * S + q) * (size_t)S;
    __bf16* prow = P + ((size_t)b * S + q) * (size_t)S;

    float v[8];
#pragma unroll
    for (int i = 0; i < 2; i++) {
        float4 r4 = *reinterpret_cast<const float4*>(rrow + t * 8 + i * 4);
        float4 m4 = *reinterpret_cast<const float4*>(mrow + t * 8 + i * 4);
        v[i * 4 + 0] = r4.x + m4.x;
        v[i * 4 + 1] = r4.y + m4.y;
        v[i * 4 + 2] = r4.z + m4.z;
        v[i * 4 + 3] = r4.w + m4.w;
    }
    float mx = v[0];
#pragma unroll
    for (int i = 1; i < 8; i++) mx = fmaxf(mx, v[i]);
#pragma unroll
    for (int off = 32; off > 0; off >>= 1) mx = fmaxf(mx, __shfl_xor(mx, off));
    __shared__ float smax[4], ssum[4];
    if (lane == 0) smax[wave] = mx;
    __syncthreads();
    mx = fmaxf(fmaxf(smax[0], smax[1]), fmaxf(smax[2], smax[3]));
    float sum = 0.f;
#pragma unroll
    for (int i = 0; i < 8; i++) { v[i] = __expf(v[i] - mx); sum += v[i]; }
#pragma unroll
    for (int off = 32; off > 0; off >>= 1) sum += __shfl_xor(sum, off);
    if (lane == 0) ssum[wave] = sum;
    __syncthreads();
    sum = ssum[0] + ssum[1] + ssum[2] + ssum[3];
    const float inv = 1.0f / sum;
    bf16x8 o;
#pragma unroll
    for (int i = 0; i < 8; i++) o[i] = (__bf16)(v[i] * inv);
    *reinterpret_cast<bf16x8*>(prow + t * 8) = o;
}

// ---------------------------------------------------------------------------
// NT GEMM: C[m,n] = sum_k A[m,k] * B[n,k] (+ bias[n])
// 128x128 tile, BK=64, 256 threads (4 waves, 64x64 each, 4x4 of 16x16x32 MFMA).
// Staging: __builtin_amdgcn_global_load_lds width=16 (async, no VGPR round-trip).
//   LDS dest is wave-uniform base + lane*16 -> unpadded [128][64] layout with
//   XOR swizzle: phys 16B-chunk = chunk ^ (row & 7)  => conflict-lite ds_read_b128.
// TRANSC: write C^T (C[n,m], ldc = ld of C^T) as packed 4x bf16
// CFLOAT: write float C, else bf16
// Requires M%128==0, N%128==0, K%64==0, 16B-aligned ptrs, lda/ldb%8==0
// ---------------------------------------------------------------------------
template <bool TRANSC, bool CFLOAT, bool BIAS>
__global__ __launch_bounds__(256) void gemm_nt_kernel(
    const __bf16* __restrict__ A, const __bf16* __restrict__ B,
    const float* __restrict__ bias, void* __restrict__ Cv,
    int K, int lda, int ldb, int ldc,
    long strideA, long strideB, long strideC) {
    const int t = threadIdx.x;
    const int lane = t & 63;
    const int wave = t >> 6;
    const int lane16 = lane & 15;
    const int quad = lane >> 4;
    const int wm = (wave >> 1) * 64;
    const int wn = (wave & 1) * 64;
    const int bm = blockIdx.y * 128;
    const int bn = blockIdx.x * 128;
    const int bz = blockIdx.z;

    A += (size_t)bz * strideA;
    B += (size_t)bz * strideB;

    __shared__ __bf16 As[128 * 64];
    __shared__ __bf16 Bs[128 * 64];

    // staging geometry: wave w stages rows w*32..w*32+31 of each tile,
    // 4 calls x (64 lanes x 16B = 8 rows) per matrix.
    const int rsub = lane >> 3;          // 0..7 row-in-group
    const int csub = lane & 7;           // physical 16B chunk
    const int lchunk = csub ^ rsub;      // logical chunk (row&7 == rsub)
    const __bf16* ga0 = A + (size_t)(bm + wave * 32 + rsub) * lda + lchunk * 8;
    const __bf16* gb0 = B + (size_t)(bn + wave * 32 + rsub) * ldb + lchunk * 8;

    f32x4 acc[4][4];
#pragma unroll
    for (int i = 0; i < 4; i++)
#pragma unroll
        for (int j = 0; j < 4; j++) acc[i][j] = (f32x4){0.f, 0.f, 0.f, 0.f};

    for (int kt = 0; kt < K; kt += 64) {
        __syncthreads();  // previous iter's ds_reads done; LDS reusable
#pragma unroll
        for (int c = 0; c < 4; c++)
            __builtin_amdgcn_global_load_lds(GPTR(ga0 + (size_t)(c * 8) * lda + kt),
                                             LPTR(&As[(wave * 32 + c * 8) * 64]), 16, 0, 0);
#pragma unroll
        for (int c = 0; c < 4; c++)
            __builtin_amdgcn_global_load_lds(GPTR(gb0 + (size_t)(c * 8) * ldb + kt),
                                             LPTR(&Bs[(wave * 32 + c * 8) * 64]), 16, 0, 0);
        __syncthreads();  // compiler emits s_waitcnt vmcnt(0) before s_barrier -> data landed
#pragma unroll
        for (int s = 0; s < 2; s++) {
            bf16x8 af[4], bfr[4];
#pragma unroll
            for (int mi = 0; mi < 4; mi++) {
                const int r = wm + mi * 16 + lane16;
                af[mi] = *reinterpret_cast<const bf16x8*>(
                    &As[r * 64 + (((s * 4 + quad) ^ (r & 7)) << 3)]);
            }
#pragma unroll
            for (int ni = 0; ni < 4; ni++) {
                const int r = wn + ni * 16 + lane16;
                bfr[ni] = *reinterpret_cast<const bf16x8*>(
                    &Bs[r * 64 + (((s * 4 + quad) ^ (r & 7)) << 3)]);
            }
#pragma unroll
            for (int mi = 0; mi < 4; mi++)
#pragma unroll
                for (int ni = 0; ni < 4; ni++)
                    acc[mi][ni] = __builtin_amdgcn_mfma_f32_16x16x32_bf16(af[mi], bfr[ni], acc[mi][ni], 0, 0, 0);
        }
    }

    // Epilogue. C/D layout: col = lane&15, row = quad*4 + reg  [m89/m91]
    __bf16* Cb = (__bf16*)Cv + (size_t)bz * strideC;
    float* Cf = (float*)Cv + (size_t)bz * strideC;
#pragma unroll
    for (int mi = 0; mi < 4; mi++) {
#pragma unroll
        for (int ni = 0; ni < 4; ni++) {
            const int cm = bm + wm + mi * 16 + quad * 4;
            const int cn = bn + wn + ni * 16 + lane16;
            const float bv = BIAS ? bias[cn] : 0.0f;
            if constexpr (TRANSC) {
                bf16x4 pk;
#pragma unroll
                for (int r = 0; r < 4; r++) pk[r] = (__bf16)(acc[mi][ni][r] + bv);
                *reinterpret_cast<bf16x4*>(Cb + (size_t)cn * ldc + cm) = pk;
            } else if constexpr (CFLOAT) {
#pragma unroll
                for (int r = 0; r < 4; r++)
                    Cf[(size_t)(cm + r) * ldc + cn] = acc[mi][ni][r] + bv;
            } else {
#pragma unroll
                for (int r = 0; r < 4; r++)
                    Cb[(size_t)(cm + r) * ldc + cn] = (__bf16)(acc[mi][ni][r] + bv);
            }
        }
    }
}

// ---------------------------------------------------------------------------
// Pipeline (W-folding: out = P @ (hidden @ (F G)^T) + (F G_b + F_b), since
// softmax rows sum to 1):
//   cvt F | transpose-cvt G | GEMM0 W=F@G | gemv b2 | cvt hidden |
//   GEMM1 Vt=(X W^T)^T | softmax P | GEMM2 out = P@V + b2
// ---------------------------------------------------------------------------
extern "C" void kernel_launch(void* const* d_in, const int* in_sizes, int n_in,
                              void* d_out, int out_size, void* d_ws, size_t ws_size,
                              hipStream_t stream) {
    const float* hidden = (const float*)d_in[0];
    const float* mask   = (const float*)d_in[1];
    const float* R      = (const float*)d_in[2];
    const float* G_w    = (const float*)d_in[3];
    const float* G_b    = (const float*)d_in[4];
    const float* F_w    = (const float*)d_in[5];
    const float* F_b    = (const float*)d_in[6];
    float* out = (float*)d_out;

    constexpr int B = 4, S = 2048, H = 1024;
    char* ws = (char*)d_ws;
    __bf16* h_bf  = (__bf16*)(ws);                   // 16 MB, dead after GEMM1
    __bf16* vt    = (__bf16*)(ws + (16ll << 20));    // 16 MB  Vt[b][o][s]
    __bf16* probs = (__bf16*)(ws + (32ll << 20));    // 32 MB  [b][q][s]
    __bf16* Wm    = (__bf16*)(ws + (32ll << 20));    // 2 MB, aliases probs (dead before softmax)
    __bf16* f_bf  = (__bf16*)(ws + (64ll << 20));    // 2 MB, dead after GEMM0
    __bf16* gt_bf = (__bf16*)(ws + (66ll << 20));    // 2 MB, dead after GEMM0
    float*  b2    = (float*)(ws + (64ll << 20));     // 4 KB, aliases f_bf (written after GEMM0)

    cvt_kernel<<<(H * H) / 8 / 256, 256, 0, stream>>>(F_w, f_bf, (long)H * H);
    transpose_cvt_kernel<<<dim3(H / 64, H / 64), 256, 0, stream>>>(G_w, gt_bf, H);

    // GEMM0: W[o][k] = sum_h F[o][h] * Gt[k][h]
    gemm_nt_kernel<false, false, false><<<dim3(H / 128, H / 128, 1), 256, 0, stream>>>(
        f_bf, gt_bf, nullptr, Wm, H, H, H, H, 0, 0, 0);

    gemv_bias_kernel<<<H, 256, 0, stream>>>(F_w, G_b, F_b, b2, H);

    cvt_kernel<<<(B * S * H) / 8 / 256, 256, 0, stream>>>(hidden, h_bf, (long)B * S * H);

    // GEMM1: Vt[b][o][s] = sum_k hidden[b][s][k] * W[o][k]   (C^T write)
    gemm_nt_kernel<true, false, false><<<dim3(H / 128, S / 128, B), 256, 0, stream>>>(
        h_bf, Wm, nullptr, vt, H, H, H, /*ldc of C^T*/ S,
        (long)S * H, 0, (long)H * S);

    // probs[b][q][s] = softmax_s(R[q][s] + mask[b][0][q][s])   (overwrites Wm, now dead)
    softmax_kernel<<<dim3(S, B), 256, 0, stream>>>(R, mask, probs, S);

    // GEMM2: out[b][q][o] = sum_s probs[b][q][s] * Vt[b][o][s] + b2[o]  (fp32 out)
    gemm_nt_kernel<false, true, true><<<dim3(H / 128, S / 128, B), 256, 0, stream>>>(
        probs, vt, b2, out, S, S, S, H,
        (long)S * S, (long)H * S, (long)S * H);
}

// Round 3
// 257.138 us; speedup vs baseline: 1.8915x; 1.0365x over previous
//
#include <hip/hip_runtime.h>
#include <hip/hip_bf16.h>

typedef __bf16 bf16x8 __attribute__((ext_vector_type(8)));
typedef __bf16 bf16x4 __attribute__((ext_vector_type(4)));
typedef float  f32x4  __attribute__((ext_vector_type(4)));
typedef float  f32x16 __attribute__((ext_vector_type(16)));

#define GPTR(p) ((__attribute__((address_space(1))) void*)(p))
#define LPTR(p) ((__attribute__((address_space(3))) void*)(p))

// ---------------------------------------------------------------------------
// f32 -> bf16 conversion, 8 elems/thread
// ---------------------------------------------------------------------------
__global__ __launch_bounds__(256) void cvt_kernel(const float* __restrict__ x,
                                                  __bf16* __restrict__ y, long n) {
    long i = ((long)blockIdx.x * 256 + threadIdx.x) * 8;
    if (i >= n) return;
    float4 a = *reinterpret_cast<const float4*>(x + i);
    float4 c = *reinterpret_cast<const float4*>(x + i + 4);
    bf16x8 o;
    o[0] = (__bf16)a.x; o[1] = (__bf16)a.y; o[2] = (__bf16)a.z; o[3] = (__bf16)a.w;
    o[4] = (__bf16)c.x; o[5] = (__bf16)c.y; o[6] = (__bf16)c.z; o[7] = (__bf16)c.w;
    *reinterpret_cast<bf16x8*>(y + i) = o;
}

// ---------------------------------------------------------------------------
// Transpose + cvt: y[c][r] = (bf16)x[r][c], x is n x n fp32. 64x64 LDS tiles.
// ---------------------------------------------------------------------------
__global__ __launch_bounds__(256) void transpose_cvt_kernel(const float* __restrict__ x,
                                                            __bf16* __restrict__ y, int n) {
    __shared__ float tile[64][65];
    const int bx = blockIdx.x * 64;
    const int by = blockIdx.y * 64;
    const int t = threadIdx.x;
    const int tr = t >> 4;
    const int tc = (t & 15) * 4;
#pragma unroll
    for (int i = 0; i < 4; i++) {
        float4 v = *reinterpret_cast<const float4*>(&x[(size_t)(by + tr + i * 16) * n + bx + tc]);
        tile[tr + i * 16][tc + 0] = v.x;
        tile[tr + i * 16][tc + 1] = v.y;
        tile[tr + i * 16][tc + 2] = v.z;
        tile[tr + i * 16][tc + 3] = v.w;
    }
    __syncthreads();
    const int wr = t >> 2;
    const int wc = (t & 3) * 16;
    bf16x8 o0, o1;
#pragma unroll
    for (int j = 0; j < 8; j++) o0[j] = (__bf16)tile[wc + j][wr];
#pragma unroll
    for (int j = 0; j < 8; j++) o1[j] = (__bf16)tile[wc + 8 + j][wr];
    *reinterpret_cast<bf16x8*>(&y[(size_t)(bx + wr) * n + by + wc]) = o0;
    *reinterpret_cast<bf16x8*>(&y[(size_t)(bx + wr) * n + by + wc + 8]) = o1;
}

// ---------------------------------------------------------------------------
// b2[o] = sum_h Fw[o][h] * Gb[h] + Fb[o]
// ---------------------------------------------------------------------------
__global__ __launch_bounds__(256) void gemv_bias_kernel(const float* __restrict__ Fw,
                                                        const float* __restrict__ Gb,
                                                        const float* __restrict__ Fb,
                                                        float* __restrict__ b2, int H) {
    const int o = blockIdx.x;
    float s = 0.f;
    for (int h = threadIdx.x; h < H; h += 256) s += Fw[(size_t)o * H + h] * Gb[h];
#pragma unroll
    for (int off = 32; off > 0; off >>= 1) s += __shfl_xor(s, off);
    __shared__ float ss[4];
    if ((threadIdx.x & 63) == 0) ss[threadIdx.x >> 6] = s;
    __syncthreads();
    if (threadIdx.x == 0) b2[o] = ss[0] + ss[1] + ss[2] + ss[3] + Fb[o];
}

// ---------------------------------------------------------------------------
// Row softmax of (R[q,:] + mask[b,0,q,:]) -> bf16 probs[b,q,:]
// ---------------------------------------------------------------------------
__global__ __launch_bounds__(256) void softmax_kernel(const float* __restrict__ R,
                                                      const float* __restrict__ mask,
                                                      __bf16* __restrict__ P, int S) {
    const int q = blockIdx.x, b = blockIdx.y;
    const int t = threadIdx.x;
    const int lane = t & 63, wave = t >> 6;
    const float* rrow = R + (size_t)q * S;
    const float* mrow = mask + ((size_t)b * S + q) * (size_t)S;
    __bf16* prow = P + ((size_t)b * S + q) * (size_t)S;

    float v[8];
#pragma unroll
    for (int i = 0; i < 2; i++) {
        float4 r4 = *reinterpret_cast<const float4*>(rrow + t * 8 + i * 4);
        float4 m4 = *reinterpret_cast<const float4*>(mrow + t * 8 + i * 4);
        v[i * 4 + 0] = r4.x + m4.x;
        v[i * 4 + 1] = r4.y + m4.y;
        v[i * 4 + 2] = r4.z + m4.z;
        v[i * 4 + 3] = r4.w + m4.w;
    }
    float mx = v[0];
#pragma unroll
    for (int i = 1; i < 8; i++) mx = fmaxf(mx, v[i]);
#pragma unroll
    for (int off = 32; off > 0; off >>= 1) mx = fmaxf(mx, __shfl_xor(mx, off));
    __shared__ float smax[4], ssum[4];
    if (lane == 0) smax[wave] = mx;
    __syncthreads();
    mx = fmaxf(fmaxf(smax[0], smax[1]), fmaxf(smax[2], smax[3]));
    float sum = 0.f;
#pragma unroll
    for (int i = 0; i < 8; i++) { v[i] = __expf(v[i] - mx); sum += v[i]; }
#pragma unroll
    for (int off = 32; off > 0; off >>= 1) sum += __shfl_xor(sum, off);
    if (lane == 0) ssum[wave] = sum;
    __syncthreads();
    sum = ssum[0] + ssum[1] + ssum[2] + ssum[3];
    const float inv = 1.0f / sum;
    bf16x8 o;
#pragma unroll
    for (int i = 0; i < 8; i++) o[i] = (__bf16)(v[i] * inv);
    *reinterpret_cast<bf16x8*>(prow + t * 8) = o;
}

// ---------------------------------------------------------------------------
// NT GEMM: C[m,n] = sum_k A[m,k] * B[n,k] (+ bias[n])
// 128x128 tile, BK=64, 256 threads; 4 waves of 64x64 = 2x2 mfma_f32_32x32x16.
// Staging: global_load_lds width=16, XOR-swizzled chunks (conflict-free, R2: 0).
// A-frag layout (32x32x16): A[m = lane&31][k = (lane>>5)*8 + j]  (16B contig)
// C/D layout: col = lane&31, row = (reg&3) + 8*(reg>>2) + 4*(lane>>5) [m74/m101]
// TRANSC: write C^T packed bf16x4; CFLOAT: fp32 C; else bf16.
// ---------------------------------------------------------------------------
template <bool TRANSC, bool CFLOAT, bool BIAS>
__global__ __launch_bounds__(256) void gemm_nt_kernel(
    const __bf16* __restrict__ A, const __bf16* __restrict__ B,
    const float* __restrict__ bias, void* __restrict__ Cv,
    int K, int lda, int ldb, int ldc,
    long strideA, long strideB, long strideC) {
    const int t = threadIdx.x;
    const int lane = t & 63;
    const int wave = t >> 6;
    const int lane31 = lane & 31;
    const int hi = lane >> 5;            // 0/1
    const int wm = (wave >> 1) * 64;
    const int wn = (wave & 1) * 64;
    const int bm = blockIdx.y * 128;
    const int bn = blockIdx.x * 128;
    const int bz = blockIdx.z;

    A += (size_t)bz * strideA;
    B += (size_t)bz * strideB;

    __shared__ __bf16 As[128 * 64];
    __shared__ __bf16 Bs[128 * 64];

    // staging: wave w stages rows w*32..w*32+31; 4 calls x (64 lanes*16B = 8 rows)
    const int rsub = lane >> 3;
    const int csub = lane & 7;
    const int lchunk = csub ^ rsub;      // logical chunk so phys = logical^(row&7)
    const __bf16* ga0 = A + (size_t)(bm + wave * 32 + rsub) * lda + lchunk * 8;
    const __bf16* gb0 = B + (size_t)(bn + wave * 32 + rsub) * ldb + lchunk * 8;

    f32x16 acc[2][2];
#pragma unroll
    for (int i = 0; i < 2; i++)
#pragma unroll
        for (int j = 0; j < 2; j++) acc[i][j] = (f32x16)(0.f);

    for (int kt = 0; kt < K; kt += 64) {
        __syncthreads();
#pragma unroll
        for (int c = 0; c < 4; c++)
            __builtin_amdgcn_global_load_lds(GPTR(ga0 + (size_t)(c * 8) * lda + kt),
                                             LPTR(&As[(wave * 32 + c * 8) * 64]), 16, 0, 0);
#pragma unroll
        for (int c = 0; c < 4; c++)
            __builtin_amdgcn_global_load_lds(GPTR(gb0 + (size_t)(c * 8) * ldb + kt),
                                             LPTR(&Bs[(wave * 32 + c * 8) * 64]), 16, 0, 0);
        __syncthreads();
#pragma unroll
        for (int s = 0; s < 4; s++) {            // 4 k-steps of 16
            bf16x8 af[2], bfr[2];
#pragma unroll
            for (int mi = 0; mi < 2; mi++) {
                const int r = wm + mi * 32 + lane31;
                af[mi] = *reinterpret_cast<const bf16x8*>(
                    &As[r * 64 + (((2 * s + hi) ^ (r & 7)) << 3)]);
            }
#pragma unroll
            for (int ni = 0; ni < 2; ni++) {
                const int r = wn + ni * 32 + lane31;
                bfr[ni] = *reinterpret_cast<const bf16x8*>(
                    &Bs[r * 64 + (((2 * s + hi) ^ (r & 7)) << 3)]);
            }
#pragma unroll
            for (int mi = 0; mi < 2; mi++)
#pragma unroll
                for (int ni = 0; ni < 2; ni++)
                    acc[mi][ni] = __builtin_amdgcn_mfma_f32_32x32x16_bf16(af[mi], bfr[ni], acc[mi][ni], 0, 0, 0);
        }
    }

    __bf16* Cb = (__bf16*)Cv + (size_t)bz * strideC;
    float* Cf = (float*)Cv + (size_t)bz * strideC;
#pragma unroll
    for (int mi = 0; mi < 2; mi++) {
#pragma unroll
        for (int ni = 0; ni < 2; ni++) {
            const int cm = bm + wm + mi * 32;
            const int cn = bn + wn + ni * 32 + lane31;
            const float bv = BIAS ? bias[cn] : 0.0f;
#pragma unroll
            for (int rq = 0; rq < 4; rq++) {
                const int rbase = rq * 8 + 4 * hi;
                if constexpr (TRANSC) {
                    bf16x4 pk;
#pragma unroll
                    for (int rr = 0; rr < 4; rr++) pk[rr] = (__bf16)(acc[mi][ni][rq * 4 + rr] + bv);
                    *reinterpret_cast<bf16x4*>(Cb + (size_t)cn * ldc + cm + rbase) = pk;
                } else if constexpr (CFLOAT) {
#pragma unroll
                    for (int rr = 0; rr < 4; rr++)
                        Cf[(size_t)(cm + rbase + rr) * ldc + cn] = acc[mi][ni][rq * 4 + rr] + bv;
                } else {
#pragma unroll
                    for (int rr = 0; rr < 4; rr++)
                        Cb[(size_t)(cm + rbase + rr) * ldc + cn] = (__bf16)(acc[mi][ni][rq * 4 + rr] + bv);
                }
            }
        }
    }
}

// ---------------------------------------------------------------------------
// Small NT GEMM for W = F @ G^T-style 1024^3: 64x64 tile (256 blocks -> full
// CU coverage), 4 waves of 32x32 (1 acc each), bf16 out, no bias.
// ---------------------------------------------------------------------------
__global__ __launch_bounds__(256) void gemm_nt64_kernel(
    const __bf16* __restrict__ A, const __bf16* __restrict__ B,
    __bf16* __restrict__ C, int K, int lda, int ldb, int ldc) {
    const int t = threadIdx.x;
    const int lane = t & 63;
    const int wave = t >> 6;
    const int lane31 = lane & 31;
    const int hi = lane >> 5;
    const int wm = (wave >> 1) * 32;
    const int wn = (wave & 1) * 32;
    const int bm = blockIdx.y * 64;
    const int bn = blockIdx.x * 64;

    __shared__ __bf16 As[64 * 64];
    __shared__ __bf16 Bs[64 * 64];

    const int rsub = lane >> 3;
    const int csub = lane & 7;
    const int lchunk = csub ^ rsub;
    const __bf16* ga0 = A + (size_t)(bm + wave * 16 + rsub) * lda + lchunk * 8;
    const __bf16* gb0 = B + (size_t)(bn + wave * 16 + rsub) * ldb + lchunk * 8;

    f32x16 acc = (f32x16)(0.f);

    for (int kt = 0; kt < K; kt += 64) {
        __syncthreads();
#pragma unroll
        for (int c = 0; c < 2; c++)
            __builtin_amdgcn_global_load_lds(GPTR(ga0 + (size_t)(c * 8) * lda + kt),
                                             LPTR(&As[(wave * 16 + c * 8) * 64]), 16, 0, 0);
#pragma unroll
        for (int c = 0; c < 2; c++)
            __builtin_amdgcn_global_load_lds(GPTR(gb0 + (size_t)(c * 8) * ldb + kt),
                                             LPTR(&Bs[(wave * 16 + c * 8) * 64]), 16, 0, 0);
        __syncthreads();
#pragma unroll
        for (int s = 0; s < 4; s++) {
            const int ra = wm + lane31;
            const int rb = wn + lane31;
            bf16x8 af = *reinterpret_cast<const bf16x8*>(
                &As[ra * 64 + (((2 * s + hi) ^ (ra & 7)) << 3)]);
            bf16x8 bfr = *reinterpret_cast<const bf16x8*>(
                &Bs[rb * 64 + (((2 * s + hi) ^ (rb & 7)) << 3)]);
            acc = __builtin_amdgcn_mfma_f32_32x32x16_bf16(af, bfr, acc, 0, 0, 0);
        }
    }

    const int cm = bm + wm;
    const int cn = bn + wn + lane31;
#pragma unroll
    for (int rq = 0; rq < 4; rq++) {
        const int rbase = rq * 8 + 4 * hi;
#pragma unroll
        for (int rr = 0; rr < 4; rr++)
            C[(size_t)(cm + rbase + rr) * ldc + cn] = (__bf16)acc[rq * 4 + rr];
    }
}

// ---------------------------------------------------------------------------
// Pipeline: cvt F | transpose-cvt G | GEMM0(64) W=F@G | gemv b2 | cvt hidden |
//           GEMM1 Vt=(X W^T)^T | softmax P | GEMM2 out = P@V + b2
// ---------------------------------------------------------------------------
extern "C" void kernel_launch(void* const* d_in, const int* in_sizes, int n_in,
                              void* d_out, int out_size, void* d_ws, size_t ws_size,
                              hipStream_t stream) {
    const float* hidden = (const float*)d_in[0];
    const float* mask   = (const float*)d_in[1];
    const float* R      = (const float*)d_in[2];
    const float* G_w    = (const float*)d_in[3];
    const float* G_b    = (const float*)d_in[4];
    const float* F_w    = (const float*)d_in[5];
    const float* F_b    = (const float*)d_in[6];
    float* out = (float*)d_out;

    constexpr int B = 4, S = 2048, H = 1024;
    char* ws = (char*)d_ws;
    __bf16* h_bf  = (__bf16*)(ws);                   // 16 MB
    __bf16* vt    = (__bf16*)(ws + (16ll << 20));    // 16 MB  Vt[b][o][s]
    __bf16* probs = (__bf16*)(ws + (32ll << 20));    // 32 MB
    __bf16* Wm    = (__bf16*)(ws + (32ll << 20));    // 2 MB, aliases probs (dead before softmax)
    __bf16* f_bf  = (__bf16*)(ws + (64ll << 20));    // 2 MB
    __bf16* gt_bf = (__bf16*)(ws + (66ll << 20));    // 2 MB
    float*  b2    = (float*)(ws + (64ll << 20));     // 4 KB, aliases f_bf (written after GEMM0)

    cvt_kernel<<<(H * H) / 8 / 256, 256, 0, stream>>>(F_w, f_bf, (long)H * H);
    transpose_cvt_kernel<<<dim3(H / 64, H / 64), 256, 0, stream>>>(G_w, gt_bf, H);

    // GEMM0: W[o][k] = sum_h F[o][h] * Gt[k][h]   (64-tile, 256 blocks)
    gemm_nt64_kernel<<<dim3(H / 64, H / 64), 256, 0, stream>>>(
        f_bf, gt_bf, Wm, H, H, H, H);

    gemv_bias_kernel<<<H, 256, 0, stream>>>(F_w, G_b, F_b, b2, H);

    cvt_kernel<<<(B * S * H) / 8 / 256, 256, 0, stream>>>(hidden, h_bf, (long)B * S * H);

    // GEMM1: Vt[b][o][s] = sum_k hidden[b][s][k] * W[o][k]   (C^T write)
    gemm_nt_kernel<true, false, false><<<dim3(H / 128, S / 128, B), 256, 0, stream>>>(
        h_bf, Wm, nullptr, vt, H, H, H, /*ldc of C^T*/ S,
        (long)S * H, 0, (long)H * S);

    softmax_kernel<<<dim3(S, B), 256, 0, stream>>>(R, mask, probs, S);

    // GEMM2: out[b][q][o] = sum_s probs[b][q][s] * Vt[b][o][s] + b2[o]
    gemm_nt_kernel<false, true, true><<<dim3(H / 128, S / 128, B), 256, 0, stream>>>(
        probs, vt, b2, out, S, S, S, H,
        (long)S * S, (long)H * S, (long)S * H);
}

// Round 4
// 241.099 us; speedup vs baseline: 2.0173x; 1.0665x over previous
//
#include <hip/hip_runtime.h>
#include <hip/hip_bf16.h>

typedef __bf16 bf16x8 __attribute__((ext_vector_type(8)));
typedef __bf16 bf16x4 __attribute__((ext_vector_type(4)));
typedef float  f32x4  __attribute__((ext_vector_type(4)));
typedef float  f32x16 __attribute__((ext_vector_type(16)));

#define GPTR(p) ((__attribute__((address_space(1))) void*)(p))
#define LPTR(p) ((__attribute__((address_space(3))) void*)(p))

// ---------------------------------------------------------------------------
// Phase A (fused, all independent): cvt hidden | cvt F_w | transpose-cvt G_w |
// gemv b2 = F_w @ G_b + F_b.  Grid = 4096 + 512 + 256 + 1024 = 5888 blocks.
// ---------------------------------------------------------------------------
__global__ __launch_bounds__(256) void phase_a_kernel(
    const float* __restrict__ hidden, __bf16* __restrict__ h_bf,
    const float* __restrict__ Fw, __bf16* __restrict__ f_bf,
    const float* __restrict__ Gw, __bf16* __restrict__ gt_bf,
    const float* __restrict__ Gb, const float* __restrict__ Fb,
    float* __restrict__ b2, int H) {
    __shared__ float tile[64][65];
    const int blk = blockIdx.x;
    const int t = threadIdx.x;

    if (blk < 4096) {                      // cvt hidden (8 elems/thread)
        long i = ((long)blk * 256 + t) * 8;
        float4 a = *reinterpret_cast<const float4*>(hidden + i);
        float4 c = *reinterpret_cast<const float4*>(hidden + i + 4);
        bf16x8 o;
        o[0] = (__bf16)a.x; o[1] = (__bf16)a.y; o[2] = (__bf16)a.z; o[3] = (__bf16)a.w;
        o[4] = (__bf16)c.x; o[5] = (__bf16)c.y; o[6] = (__bf16)c.z; o[7] = (__bf16)c.w;
        *reinterpret_cast<bf16x8*>(h_bf + i) = o;
    } else if (blk < 4608) {               // cvt F_w
        long i = ((long)(blk - 4096) * 256 + t) * 8;
        float4 a = *reinterpret_cast<const float4*>(Fw + i);
        float4 c = *reinterpret_cast<const float4*>(Fw + i + 4);
        bf16x8 o;
        o[0] = (__bf16)a.x; o[1] = (__bf16)a.y; o[2] = (__bf16)a.z; o[3] = (__bf16)a.w;
        o[4] = (__bf16)c.x; o[5] = (__bf16)c.y; o[6] = (__bf16)c.z; o[7] = (__bf16)c.w;
        *reinterpret_cast<bf16x8*>(f_bf + i) = o;
    } else if (blk < 4864) {               // transpose-cvt G_w (64x64 tiles)
        const int id = blk - 4608;
        const int bx = (id & 15) * 64;
        const int by = (id >> 4) * 64;
        const int tr = t >> 4;
        const int tc = (t & 15) * 4;
#pragma unroll
        for (int i = 0; i < 4; i++) {
            float4 v = *reinterpret_cast<const float4*>(&Gw[(size_t)(by + tr + i * 16) * H + bx + tc]);
            tile[tr + i * 16][tc + 0] = v.x;
            tile[tr + i * 16][tc + 1] = v.y;
            tile[tr + i * 16][tc + 2] = v.z;
            tile[tr + i * 16][tc + 3] = v.w;
        }
        __syncthreads();
        const int wr = t >> 2;
        const int wc = (t & 3) * 16;
        bf16x8 o0, o1;
#pragma unroll
        for (int j = 0; j < 8; j++) o0[j] = (__bf16)tile[wc + j][wr];
#pragma unroll
        for (int j = 0; j < 8; j++) o1[j] = (__bf16)tile[wc + 8 + j][wr];
        *reinterpret_cast<bf16x8*>(&gt_bf[(size_t)(bx + wr) * H + by + wc]) = o0;
        *reinterpret_cast<bf16x8*>(&gt_bf[(size_t)(bx + wr) * H + by + wc + 8]) = o1;
    } else {                               // gemv: b2[o] = Fw[o,:]·Gb + Fb[o]
        const int o = blk - 4864;
        float s = 0.f;
        for (int h = t; h < H; h += 256) s += Fw[(size_t)o * H + h] * Gb[h];
#pragma unroll
        for (int off = 32; off > 0; off >>= 1) s += __shfl_xor(s, off);
        __shared__ float ss[4];
        if ((t & 63) == 0) ss[t >> 6] = s;
        __syncthreads();
        if (t == 0) b2[o] = ss[0] + ss[1] + ss[2] + ss[3] + Fb[o];
    }
}

// ---------------------------------------------------------------------------
// Phase B (fused): GEMM0 W = F @ G^T (64x64 tiles, blocks 0..255) ||
// softmax rows (blocks 256..8447) — independent, overlap on the machine.
// ---------------------------------------------------------------------------
__global__ __launch_bounds__(256) void phase_b_kernel(
    const __bf16* __restrict__ f_bf, const __bf16* __restrict__ gt_bf,
    __bf16* __restrict__ Wm, const float* __restrict__ R,
    const float* __restrict__ mask, __bf16* __restrict__ P, int H, int S) {
    const int blk = blockIdx.x;
    const int t = threadIdx.x;

    if (blk < 256) {  // ---- GEMM0: W[o][k] = sum_h F[o][h]*Gt[k][h]
        __shared__ __bf16 As[64 * 64];
        __shared__ __bf16 Bs[64 * 64];
        const int lane = t & 63;
        const int wave = t >> 6;
        const int lane31 = lane & 31;
        const int hi = lane >> 5;
        const int wm = (wave >> 1) * 32;
        const int wn = (wave & 1) * 32;
        const int bm = (blk >> 4) * 64;
        const int bn = (blk & 15) * 64;

        const int rsub = lane >> 3;
        const int csub = lane & 7;
        const int lchunk = csub ^ rsub;
        const __bf16* ga0 = f_bf + (size_t)(bm + wave * 16 + rsub) * H + lchunk * 8;
        const __bf16* gb0 = gt_bf + (size_t)(bn + wave * 16 + rsub) * H + lchunk * 8;

        f32x16 acc = (f32x16)(0.f);
        for (int kt = 0; kt < H; kt += 64) {
            __syncthreads();
#pragma unroll
            for (int c = 0; c < 2; c++)
                __builtin_amdgcn_global_load_lds(GPTR(ga0 + (size_t)(c * 8) * H + kt),
                                                 LPTR(&As[(wave * 16 + c * 8) * 64]), 16, 0, 0);
#pragma unroll
            for (int c = 0; c < 2; c++)
                __builtin_amdgcn_global_load_lds(GPTR(gb0 + (size_t)(c * 8) * H + kt),
                                                 LPTR(&Bs[(wave * 16 + c * 8) * 64]), 16, 0, 0);
            __syncthreads();
#pragma unroll
            for (int s = 0; s < 4; s++) {
                const int ra = wm + lane31;
                const int rb = wn + lane31;
                bf16x8 af = *reinterpret_cast<const bf16x8*>(
                    &As[ra * 64 + (((2 * s + hi) ^ (ra & 7)) << 3)]);
                bf16x8 bfr = *reinterpret_cast<const bf16x8*>(
                    &Bs[rb * 64 + (((2 * s + hi) ^ (rb & 7)) << 3)]);
                acc = __builtin_amdgcn_mfma_f32_32x32x16_bf16(af, bfr, acc, 0, 0, 0);
            }
        }
        const int cm = bm + wm;
        const int cn = bn + wn + lane31;
#pragma unroll
        for (int rq = 0; rq < 4; rq++) {
            const int rbase = rq * 8 + 4 * hi;
#pragma unroll
            for (int rr = 0; rr < 4; rr++)
                Wm[(size_t)(cm + rbase + rr) * H + cn] = (__bf16)acc[rq * 4 + rr];
        }
    } else {          // ---- softmax row
        const int id = blk - 256;
        const int b = id >> 11;
        const int q = id & 2047;
        const int lane = t & 63, wave = t >> 6;
        const float* rrow = R + (size_t)q * S;
        const float* mrow = mask + ((size_t)b * S + q) * (size_t)S;
        __bf16* prow = P + ((size_t)b * S + q) * (size_t)S;

        float v[8];
#pragma unroll
        for (int i = 0; i < 2; i++) {
            float4 r4 = *reinterpret_cast<const float4*>(rrow + t * 8 + i * 4);
            float4 m4 = *reinterpret_cast<const float4*>(mrow + t * 8 + i * 4);
            v[i * 4 + 0] = r4.x + m4.x;
            v[i * 4 + 1] = r4.y + m4.y;
            v[i * 4 + 2] = r4.z + m4.z;
            v[i * 4 + 3] = r4.w + m4.w;
        }
        float mx = v[0];
#pragma unroll
        for (int i = 1; i < 8; i++) mx = fmaxf(mx, v[i]);
#pragma unroll
        for (int off = 32; off > 0; off >>= 1) mx = fmaxf(mx, __shfl_xor(mx, off));
        __shared__ float smax[4], ssum[4];
        if (lane == 0) smax[wave] = mx;
        __syncthreads();
        mx = fmaxf(fmaxf(smax[0], smax[1]), fmaxf(smax[2], smax[3]));
        float sum = 0.f;
#pragma unroll
        for (int i = 0; i < 8; i++) { v[i] = __expf(v[i] - mx); sum += v[i]; }
#pragma unroll
        for (int off = 32; off > 0; off >>= 1) sum += __shfl_xor(sum, off);
        if (lane == 0) ssum[wave] = sum;
        __syncthreads();
        sum = ssum[0] + ssum[1] + ssum[2] + ssum[3];
        const float inv = 1.0f / sum;
        bf16x8 o;
#pragma unroll
        for (int i = 0; i < 8; i++) o[i] = (__bf16)(v[i] * inv);
        *reinterpret_cast<bf16x8*>(prow + t * 8) = o;
    }
}

// ---------------------------------------------------------------------------
// NT GEMM: C[m,n] = sum_k A[m,k]*B[n,k] (+ bias[n])
// 128x128 tile, BK=64, 4 waves of 64x64 = 2x2 mfma_f32_32x32x16.
// Staging: global_load_lds w16, XOR-swizzled chunks.
// TRANSC: C^T staged through LDS (stride 130 -> conflict-free) then stored as
//   coalesced 16B rows (fixes 8B-scatter write amplification).
// SWZ: 1-D grid, XCD-aware decode (id%8 = XCD heuristic): each XCD gets one
//   (b, q-half) x all 8 n-blocks -> probs/vt tile reuse within one L2.
// ---------------------------------------------------------------------------
template <bool TRANSC, bool CFLOAT, bool BIAS, bool SWZ>
__global__ __launch_bounds__(256) void gemm_nt_kernel(
    const __bf16* __restrict__ A, const __bf16* __restrict__ B,
    const float* __restrict__ bias, void* __restrict__ Cv,
    int K, int lda, int ldb, int ldc,
    long strideA, long strideB, long strideC) {
    const int t = threadIdx.x;
    const int lane = t & 63;
    const int wave = t >> 6;
    const int lane31 = lane & 31;
    const int hi = lane >> 5;
    const int wm = (wave >> 1) * 64;
    const int wn = (wave & 1) * 64;
    int bm, bn, bz;
    if constexpr (SWZ) {
        // grid = 512: xcd = id&7 -> b = xcd>>1, q-half = xcd&1; slot = id>>3:
        // q = half*8 + slot>>3 (16 q-blocks), n = slot&7 (8 n-blocks)
        const int id = blockIdx.x;
        const int xcd = id & 7;
        const int slot = id >> 3;
        bz = xcd >> 1;
        bm = ((xcd & 1) * 8 + (slot >> 3)) * 128;
        bn = (slot & 7) * 128;
    } else {
        bm = blockIdx.y * 128;
        bn = blockIdx.x * 128;
        bz = blockIdx.z;
    }

    A += (size_t)bz * strideA;
    B += (size_t)bz * strideB;

    __shared__ __bf16 smem[TRANSC ? 16640 : 16384];
    __bf16* As = smem;
    __bf16* Bs = smem + 8192;

    const int rsub = lane >> 3;
    const int csub = lane & 7;
    const int lchunk = csub ^ rsub;
    const __bf16* ga0 = A + (size_t)(bm + wave * 32 + rsub) * lda + lchunk * 8;
    const __bf16* gb0 = B + (size_t)(bn + wave * 32 + rsub) * ldb + lchunk * 8;

    f32x16 acc[2][2];
#pragma unroll
    for (int i = 0; i < 2; i++)
#pragma unroll
        for (int j = 0; j < 2; j++) acc[i][j] = (f32x16)(0.f);

    for (int kt = 0; kt < K; kt += 64) {
        __syncthreads();
#pragma unroll
        for (int c = 0; c < 4; c++)
            __builtin_amdgcn_global_load_lds(GPTR(ga0 + (size_t)(c * 8) * lda + kt),
                                             LPTR(&As[(wave * 32 + c * 8) * 64]), 16, 0, 0);
#pragma unroll
        for (int c = 0; c < 4; c++)
            __builtin_amdgcn_global_load_lds(GPTR(gb0 + (size_t)(c * 8) * ldb + kt),
                                             LPTR(&Bs[(wave * 32 + c * 8) * 64]), 16, 0, 0);
        __syncthreads();
#pragma unroll
        for (int s = 0; s < 4; s++) {
            bf16x8 af[2], bfr[2];
#pragma unroll
            for (int mi = 0; mi < 2; mi++) {
                const int r = wm + mi * 32 + lane31;
                af[mi] = *reinterpret_cast<const bf16x8*>(
                    &As[r * 64 + (((2 * s + hi) ^ (r & 7)) << 3)]);
            }
#pragma unroll
            for (int ni = 0; ni < 2; ni++) {
                const int r = wn + ni * 32 + lane31;
                bfr[ni] = *reinterpret_cast<const bf16x8*>(
                    &Bs[r * 64 + (((2 * s + hi) ^ (r & 7)) << 3)]);
            }
#pragma unroll
            for (int mi = 0; mi < 2; mi++)
#pragma unroll
                for (int ni = 0; ni < 2; ni++)
                    acc[mi][ni] = __builtin_amdgcn_mfma_f32_32x32x16_bf16(af[mi], bfr[ni], acc[mi][ni], 0, 0, 0);
        }
    }

    // Epilogue. C/D: col = lane&31, row = (reg&3)+8*(reg>>2)+4*(lane>>5)
    if constexpr (TRANSC) {
        // stage C^T tile [n 128][m 128] in LDS (stride 130: bank = n + m/2, 2-way max)
        __syncthreads();
        __bf16* sC = smem;
#pragma unroll
        for (int mi = 0; mi < 2; mi++)
#pragma unroll
            for (int ni = 0; ni < 2; ni++)
#pragma unroll
                for (int rq = 0; rq < 4; rq++) {
                    const int n_l = wn + ni * 32 + lane31;
                    const int m_l = wm + mi * 32 + rq * 8 + 4 * hi;
                    bf16x4 pk;
#pragma unroll
                    for (int rr = 0; rr < 4; rr++) pk[rr] = (__bf16)acc[mi][ni][rq * 4 + rr];
                    *reinterpret_cast<bf16x4*>(&sC[n_l * 130 + m_l]) = pk;
                }
        __syncthreads();
        __bf16* Ct = (__bf16*)Cv + (size_t)bz * strideC;
        const int col = (t & 15) * 8;
#pragma unroll
        for (int p = 0; p < 8; p++) {
            const int row = p * 16 + (t >> 4);
            bf16x8 v = *reinterpret_cast<const bf16x8*>(&sC[row * 130 + col]);
            *reinterpret_cast<bf16x8*>(Ct + (size_t)(bn + row) * ldc + bm + col) = v;
        }
    } else {
        __bf16* Cb = (__bf16*)Cv + (size_t)bz * strideC;
        float* Cf = (float*)Cv + (size_t)bz * strideC;
#pragma unroll
        for (int mi = 0; mi < 2; mi++)
#pragma unroll
            for (int ni = 0; ni < 2; ni++) {
                const int cm = bm + wm + mi * 32;
                const int cn = bn + wn + ni * 32 + lane31;
                const float bv = BIAS ? bias[cn] : 0.0f;
#pragma unroll
                for (int rq = 0; rq < 4; rq++) {
                    const int rbase = rq * 8 + 4 * hi;
                    if constexpr (CFLOAT) {
#pragma unroll
                        for (int rr = 0; rr < 4; rr++)
                            Cf[(size_t)(cm + rbase + rr) * ldc + cn] = acc[mi][ni][rq * 4 + rr] + bv;
                    } else {
#pragma unroll
                        for (int rr = 0; rr < 4; rr++)
                            Cb[(size_t)(cm + rbase + rr) * ldc + cn] = (__bf16)(acc[mi][ni][rq * 4 + rr] + bv);
                    }
                }
            }
    }
}

// ---------------------------------------------------------------------------
// Pipeline: A[preproc fused] -> B[GEMM0 || softmax] -> GEMM1 Vt -> GEMM2 out
// (W-fold: out = P @ (X (F G)^T) + (F G_b + F_b), softmax rows sum to 1)
// ---------------------------------------------------------------------------
extern "C" void kernel_launch(void* const* d_in, const int* in_sizes, int n_in,
                              void* d_out, int out_size, void* d_ws, size_t ws_size,
                              hipStream_t stream) {
    const float* hidden = (const float*)d_in[0];
    const float* mask   = (const float*)d_in[1];
    const float* R      = (const float*)d_in[2];
    const float* G_w    = (const float*)d_in[3];
    const float* G_b    = (const float*)d_in[4];
    const float* F_w    = (const float*)d_in[5];
    const float* F_b    = (const float*)d_in[6];
    float* out = (float*)d_out;

    constexpr int B = 4, S = 2048, H = 1024;
    char* ws = (char*)d_ws;
    __bf16* h_bf  = (__bf16*)(ws);                   // 16 MB
    __bf16* vt    = (__bf16*)(ws + (16ll << 20));    // 16 MB  Vt[b][o][s]
    __bf16* probs = (__bf16*)(ws + (32ll << 20));    // 32 MB
    __bf16* f_bf  = (__bf16*)(ws + (64ll << 20));    // 2 MB
    __bf16* gt_bf = (__bf16*)(ws + (66ll << 20));    // 2 MB
    __bf16* Wm    = (__bf16*)(ws + (68ll << 20));    // 2 MB
    float*  b2    = (float*)(ws + (70ll << 20));     // 4 KB

    // Phase A: all preprocessing, independent
    phase_a_kernel<<<5888, 256, 0, stream>>>(hidden, h_bf, F_w, f_bf, G_w, gt_bf,
                                             G_b, F_b, b2, H);

    // Phase B: GEMM0 (256 blocks) || softmax (8192 blocks)
    phase_b_kernel<<<256 + B * S, 256, 0, stream>>>(f_bf, gt_bf, Wm, R, mask, probs, H, S);

    // GEMM1: Vt[b][o][s] = sum_k hidden[b][s][k] * W[o][k]  (C^T via LDS)
    gemm_nt_kernel<true, false, false, false><<<dim3(H / 128, S / 128, B), 256, 0, stream>>>(
        h_bf, Wm, nullptr, vt, H, H, H, /*ldc of C^T*/ S,
        (long)S * H, 0, (long)H * S);

    // GEMM2: out[b][q][o] = sum_s probs[b][q][s] * Vt[b][o][s] + b2[o]  (XCD swizzle)
    gemm_nt_kernel<false, true, true, true><<<512, 256, 0, stream>>>(
        probs, vt, b2, out, S, S, S, H,
        (long)S * S, (long)H * S, (long)S * H);
}